// Round 2
// baseline (631.616 us; speedup 1.0000x reference)
//
#include <hip/hip_runtime.h>
#include <stdint.h>

#define S 128
#define R 256
#define CM 256
#define CZ 128
#define H 8
#define D 32

// ---------- helpers ----------
__device__ __forceinline__ float wsum(float v) {
#pragma unroll
  for (int o = 32; o > 0; o >>= 1) v += __shfl_xor(v, o, 64);
  return v;
}
// bf16 (stored as ushort bits) <-> fp32
__device__ __forceinline__ float bl(unsigned u) { return __uint_as_float(u << 16); }
__device__ __forceinline__ float bh(unsigned u) { return __uint_as_float(u & 0xffff0000u); }
__device__ __forceinline__ unsigned short f2bb(float f) {
  unsigned u = __float_as_uint(f);
  return (unsigned short)((u + 0x7fffu + ((u >> 16) & 1u)) >> 16);
}

// ---------- kernel 1: pair bias  zb[h][i][j] = LN(z[i,j,:]) . wz[:,h] ----------
__global__ __launch_bounds__(256) void k_zbias(const float* __restrict__ z,
                                               const float* __restrict__ lng,
                                               const float* __restrict__ lnb,
                                               const float* __restrict__ wz,
                                               float* __restrict__ zb) {
  int pair = blockIdx.x * 4 + (threadIdx.x >> 6);  // (i,j) flattened, 0..65535
  int lane = threadIdx.x & 63;
  const float* zrow = z + (size_t)pair * CZ;
  float x0 = zrow[lane], x1 = zrow[lane + 64];
  float sum = wsum(x0 + x1);
  float ssq = wsum(x0 * x0 + x1 * x1);
  float mu = sum * (1.0f / CZ);
  float var = ssq * (1.0f / CZ) - mu * mu;
  float rs = rsqrtf(var + 1e-5f);
  float n0 = (x0 - mu) * rs * lng[lane] + lnb[lane];
  float n1 = (x1 - mu) * rs * lng[lane + 64] + lnb[lane + 64];
  float ph[8];
#pragma unroll
  for (int h = 0; h < 8; h++)
    ph[h] = n0 * wz[lane * 8 + h] + n1 * wz[(lane + 64) * 8 + h];
#pragma unroll
  for (int h = 0; h < 8; h++) ph[h] = wsum(ph[h]);
  if (lane == 0) {
#pragma unroll
    for (int h = 0; h < 8; h++) zb[h * (R * R) + pair] = ph[h];
  }
}

// ---------- kernel 2: LN(m) + Q/K/V/G projections ----------
// 16 rows per block. q/k bf16 [s][h][r][d]; v fp32 [s][h][r][d]; g fp32 [s*r][h*d].
__global__ __launch_bounds__(256) void k_proj(const float* __restrict__ m,
                                              const float* __restrict__ lng,
                                              const float* __restrict__ lnb,
                                              const float* __restrict__ wq,
                                              const float* __restrict__ wk,
                                              const float* __restrict__ wv,
                                              const float* __restrict__ wg,
                                              const float* __restrict__ bg,
                                              unsigned short* __restrict__ qb,
                                              unsigned short* __restrict__ kb,
                                              float* __restrict__ vb,
                                              float* __restrict__ gb) {
  __shared__ float mm[16][CM];
  int tid = threadIdx.x;
  int grow0 = blockIdx.x * 16;
  int s = grow0 >> 8;  // 16 consecutive rows never cross an s boundary
#pragma unroll
  for (int r = 0; r < 16; r++) mm[r][tid] = m[(size_t)(grow0 + r) * CM + tid];
  __syncthreads();
  int w = tid >> 6, lane = tid & 63;
#pragma unroll
  for (int i = 0; i < 4; i++) {
    int r = w * 4 + i;
    float v0 = mm[r][lane], v1 = mm[r][lane + 64];
    float v2 = mm[r][lane + 128], v3 = mm[r][lane + 192];
    float sum = wsum(v0 + v1 + v2 + v3);
    float ssq = wsum(v0 * v0 + v1 * v1 + v2 * v2 + v3 * v3);
    float mu = sum * (1.0f / CM);
    float rs = rsqrtf(ssq * (1.0f / CM) - mu * mu + 1e-5f);
    mm[r][lane]       = (v0 - mu) * rs * lng[lane]       + lnb[lane];
    mm[r][lane + 64]  = (v1 - mu) * rs * lng[lane + 64]  + lnb[lane + 64];
    mm[r][lane + 128] = (v2 - mu) * rs * lng[lane + 128] + lnb[lane + 128];
    mm[r][lane + 192] = (v3 - mu) * rs * lng[lane + 192] + lnb[lane + 192];
  }
  __syncthreads();
  int t = tid;  // output index hd = h*32+d
  float aq[16], ak[16], av[16], ag[16];
#pragma unroll
  for (int r = 0; r < 16; r++) { aq[r] = 0.f; ak[r] = 0.f; av[r] = 0.f; ag[r] = 0.f; }
#pragma unroll 2
  for (int c = 0; c < CM; c++) {
    float wqv = wq[c * 256 + t], wkv = wk[c * 256 + t];
    float wvv = wv[c * 256 + t], wgv = wg[c * 256 + t];
#pragma unroll
    for (int r = 0; r < 16; r++) {
      float mv = mm[r][c];
      aq[r] = fmaf(mv, wqv, aq[r]);
      ak[r] = fmaf(mv, wkv, ak[r]);
      av[r] = fmaf(mv, wvv, av[r]);
      ag[r] = fmaf(mv, wgv, ag[r]);
    }
  }
  int h = t >> 5, d = t & 31;
  const float qscale = 0.17677669529663687f;  // 1/sqrt(32)
  float bgv = bg[t];
#pragma unroll
  for (int r = 0; r < 16; r++) {
    int grow = grow0 + r;
    int rr = grow & 255;
    size_t qi = ((size_t)(s * H + h) * R + rr) * D + d;
    qb[qi] = f2bb(aq[r] * qscale);
    kb[qi] = f2bb(ak[r]);
    vb[qi] = av[r];
    float gv = ag[r] + bgv;
    gb[(size_t)grow * 256 + t] = 1.0f / (1.0f + __expf(-gv));
  }
}

// ---------- kernel 3: attention per (s,h) ----------
__global__ __launch_bounds__(256) void k_attn(const unsigned short* __restrict__ qb,
                                              const unsigned short* __restrict__ kb,
                                              const float* __restrict__ vb,
                                              const float* __restrict__ gb,
                                              const float* __restrict__ zb,
                                              const float* __restrict__ mask,
                                              float* __restrict__ ob) {
  __shared__ float4 Kt[R][8];
  __shared__ float4 Vt[R][8];
  int s = blockIdx.x >> 3, h = blockIdx.x & 7;
  int tid = threadIdx.x;
  size_t base = (size_t)(s * H + h) * R * D;  // element offset
  const uint4* kv4 = (const uint4*)(kb + base);
#pragma unroll
  for (int j = 0; j < 4; j++) {
    int f = tid + j * 256;      // uint4 index, 0..1023 (8 bf16 each)
    int row = f >> 2;
    int slot = (f & 3) * 2;
    uint4 u = kv4[f];
    Kt[row][slot]     = make_float4(bl(u.x), bh(u.x), bl(u.y), bh(u.y));
    Kt[row][slot + 1] = make_float4(bl(u.z), bh(u.z), bl(u.w), bh(u.w));
  }
  const float4* vv4 = (const float4*)(vb + base);
#pragma unroll
  for (int j = 0; j < 8; j++) {
    int f = tid + j * 256;      // float4 index, 0..2047
    Vt[f >> 3][f & 7] = vv4[f];
  }
  __syncthreads();
  int q = tid;
  float4 qr[8];
  const uint4* qv4 = (const uint4*)(qb + base + (size_t)q * D);
#pragma unroll
  for (int j = 0; j < 4; j++) {
    uint4 u = qv4[j];
    qr[j * 2]     = make_float4(bl(u.x), bh(u.x), bl(u.y), bh(u.y));
    qr[j * 2 + 1] = make_float4(bl(u.z), bh(u.z), bl(u.w), bh(u.w));
  }
  const float* zrow = zb + (size_t)h * R * R + (size_t)q * R;
  const float* mrow = mask + (size_t)s * R;
  float4 acc[8];
#pragma unroll
  for (int j = 0; j < 8; j++) acc[j] = make_float4(0.f, 0.f, 0.f, 0.f);
  float l = 0.f;
#pragma unroll 4
  for (int k = 0; k < R; k++) {
    float sc = 0.f;
#pragma unroll
    for (int j = 0; j < 8; j++) {
      float4 kv = Kt[k][j];
      sc = fmaf(qr[j].x, kv.x, sc);
      sc = fmaf(qr[j].y, kv.y, sc);
      sc = fmaf(qr[j].z, kv.z, sc);
      sc = fmaf(qr[j].w, kv.w, sc);
    }
    sc += zrow[k] + 1e9f * (mrow[k] - 1.0f);
    float p = __expf(sc);  // scores are O(1): no max-subtraction needed
    l += p;
#pragma unroll
    for (int j = 0; j < 8; j++) {
      float4 vv = Vt[k][j];
      acc[j].x = fmaf(p, vv.x, acc[j].x);
      acc[j].y = fmaf(p, vv.y, acc[j].y);
      acc[j].z = fmaf(p, vv.z, acc[j].z);
      acc[j].w = fmaf(p, vv.w, acc[j].w);
    }
  }
  float inv = 1.0f / l;
  size_t gbase = ((size_t)(s * R + q)) * (H * D) + h * D;
  const float4* g4 = (const float4*)(gb + gbase);
  float4* o4 = (float4*)(ob + gbase);
#pragma unroll
  for (int j = 0; j < 8; j++) {
    float4 gv = g4[j];
    float4 a = acc[j];
    o4[j] = make_float4(a.x * inv * gv.x, a.y * inv * gv.y,
                        a.z * inv * gv.z, a.w * inv * gv.w);
  }
}

// ---------- kernel 4: out = (o*g) @ wo + bo ----------
__global__ __launch_bounds__(256) void k_out(const float* __restrict__ ob,
                                             const float* __restrict__ wo,
                                             const float* __restrict__ bo,
                                             float* __restrict__ out) {
  __shared__ float og[16][256];
  int tid = threadIdx.x;
  int grow0 = blockIdx.x * 16;
  const float4* ov = (const float4*)(ob + (size_t)grow0 * 256);
#pragma unroll
  for (int j = 0; j < 4; j++) {
    int f = tid + j * 256;   // float4 index, 0..1023
    int row = f >> 6;        // 64 float4 per row
    int c0 = (f & 63) * 4;
    float4 u = ov[f];
    og[row][c0 + 0] = u.x; og[row][c0 + 1] = u.y;
    og[row][c0 + 2] = u.z; og[row][c0 + 3] = u.w;
  }
  __syncthreads();
  int c = tid;
  float acc[16];
#pragma unroll
  for (int r = 0; r < 16; r++) acc[r] = 0.f;
#pragma unroll 2
  for (int hd = 0; hd < 256; hd++) {
    float wv = wo[hd * 256 + c];
#pragma unroll
    for (int r = 0; r < 16; r++) acc[r] = fmaf(og[r][hd], wv, acc[r]);
  }
  float bov = bo[c];
#pragma unroll
  for (int r = 0; r < 16; r++)
    out[(size_t)(grow0 + r) * 256 + c] = acc[r] + bov;
}

extern "C" void kernel_launch(void* const* d_in, const int* in_sizes, int n_in,
                              void* d_out, int out_size, void* d_ws, size_t ws_size,
                              hipStream_t stream) {
  const float* m      = (const float*)d_in[0];
  const float* z      = (const float*)d_in[1];
  const float* mask   = (const float*)d_in[2];
  const float* ln_m_g = (const float*)d_in[3];
  const float* ln_m_b = (const float*)d_in[4];
  const float* ln_z_g = (const float*)d_in[5];
  const float* ln_z_b = (const float*)d_in[6];
  const float* wz     = (const float*)d_in[7];
  const float* wq     = (const float*)d_in[8];
  const float* wk     = (const float*)d_in[9];
  const float* wv     = (const float*)d_in[10];
  const float* wg     = (const float*)d_in[11];
  const float* bg     = (const float*)d_in[12];
  const float* wo     = (const float*)d_in[13];
  const float* bo     = (const float*)d_in[14];
  float* out = (float*)d_out;

  char* ws = (char*)d_ws;
  const size_t MiB = 1u << 20;
  float* zbuf          = (float*)(ws);                 // 2 MiB (512K floats)
  unsigned short* qb   = (unsigned short*)(ws + 2  * MiB);   // 16 MiB
  unsigned short* kb   = (unsigned short*)(ws + 18 * MiB);   // 16 MiB
  float* vb            = (float*)(ws + 34 * MiB);            // 32 MiB
  float* gb            = (float*)(ws + 66 * MiB);            // 32 MiB
  float* obuf          = (float*)(ws + 98 * MiB);            // 32 MiB -> 130 total
  (void)in_sizes; (void)n_in; (void)out_size; (void)ws_size;

  k_zbias<<<(R * R) / 4, 256, 0, stream>>>(z, ln_z_g, ln_z_b, wz, zbuf);
  k_proj<<<(S * R) / 16, 256, 0, stream>>>(m, ln_m_g, ln_m_b, wq, wk, wv, wg, bg,
                                           qb, kb, vb, gb);
  k_attn<<<S * H, 256, 0, stream>>>(qb, kb, vb, gb, zbuf, mask, obuf);
  k_out<<<(S * R) / 16, 256, 0, stream>>>(obuf, wo, bo, out);
}

// Round 3
// 204.223 us; speedup vs baseline: 3.0928x; 3.0928x over previous
//
#include <hip/hip_runtime.h>
#include <stdint.h>

#define S 128
#define R 256
#define CM 256
#define CZ 128
#define H 8
#define D 32

typedef __attribute__((ext_vector_type(8))) short short8;
typedef __attribute__((ext_vector_type(4))) float f32x4;
typedef unsigned short u16;

// ---------- helpers ----------
__device__ __forceinline__ float wsum(float v) {
#pragma unroll
  for (int o = 32; o > 0; o >>= 1) v += __shfl_xor(v, o, 64);
  return v;
}
__device__ __forceinline__ u16 f2bb(float f) {
  unsigned u = __float_as_uint(f);
  return (u16)((u + 0x7fffu + ((u >> 16) & 1u)) >> 16);
}
__device__ __forceinline__ float b2f(u16 u) {
  return __uint_as_float(((unsigned)u) << 16);
}

// ---------- kernel 0: weights -> bf16, transposed [hd'][c]; qscale folded ----------
__global__ __launch_bounds__(256) void k_prep(const float* __restrict__ wq,
                                              const float* __restrict__ wk,
                                              const float* __restrict__ wv,
                                              const float* __restrict__ wg,
                                              const float* __restrict__ wo,
                                              u16* __restrict__ wcat_t,
                                              u16* __restrict__ wot) {
  __shared__ float t[64][65];
  int mat = blockIdx.y;  // 0..4
  const float* src = (mat == 0) ? wq : (mat == 1) ? wk : (mat == 2) ? wv
                     : (mat == 3) ? wg : wo;
  float scale = (mat == 0) ? 0.17677669529663687f : 1.0f;  // 1/sqrt(D) into wq
  u16* dst = (mat < 4) ? (wcat_t + mat * 256 * 256) : wot;
  int ti = blockIdx.x >> 2, tj = blockIdx.x & 3;
  int tid = threadIdx.x;
  int cc = tid & 63, rr4 = tid >> 6;
#pragma unroll
  for (int it = 0; it < 16; it++) {
    int ic = it * 4 + rr4;
    t[ic][cc] = src[(tj * 64 + ic) * 256 + ti * 64 + cc];
  }
  __syncthreads();
#pragma unroll
  for (int it = 0; it < 16; it++) {
    int oh = it * 4 + rr4;
    dst[(ti * 64 + oh) * 256 + tj * 64 + cc] = f2bb(t[cc][oh] * scale);
  }
}

// ---------- kernel 1: pair bias  zb[h][i][j] = LN(z[i,j,:]) . wz[:,h] ----------
__global__ __launch_bounds__(256) void k_zbias(const float* __restrict__ z,
                                               const float* __restrict__ lng,
                                               const float* __restrict__ lnb,
                                               const float* __restrict__ wz,
                                               float* __restrict__ zb) {
  int pair = blockIdx.x * 4 + (threadIdx.x >> 6);
  int lane = threadIdx.x & 63;
  const float* zrow = z + (size_t)pair * CZ;
  float x0 = zrow[lane], x1 = zrow[lane + 64];
  float sum = wsum(x0 + x1);
  float ssq = wsum(x0 * x0 + x1 * x1);
  float mu = sum * (1.0f / CZ);
  float rs = rsqrtf(ssq * (1.0f / CZ) - mu * mu + 1e-5f);
  float n0 = (x0 - mu) * rs * lng[lane] + lnb[lane];
  float n1 = (x1 - mu) * rs * lng[lane + 64] + lnb[lane + 64];
  float ph[8];
#pragma unroll
  for (int h = 0; h < 8; h++)
    ph[h] = n0 * wz[lane * 8 + h] + n1 * wz[(lane + 64) * 8 + h];
#pragma unroll
  for (int h = 0; h < 8; h++) ph[h] = wsum(ph[h]);
  if (lane == 0) {
#pragma unroll
    for (int h = 0; h < 8; h++) zb[h * (R * R) + pair] = ph[h];
  }
}

// ---------- kernel 2: LN(m) -> bf16 ----------
__global__ __launch_bounds__(256) void k_lnm(const float* __restrict__ m,
                                             const float* __restrict__ g,
                                             const float* __restrict__ b,
                                             u16* __restrict__ mln) {
  int w = threadIdx.x >> 6, lane = threadIdx.x & 63;
  size_t row = (size_t)blockIdx.x * 4 + w;
  const float4 v = *(const float4*)(m + row * 256 + lane * 4);
  float sum = wsum(v.x + v.y + v.z + v.w);
  float ssq = wsum(v.x * v.x + v.y * v.y + v.z * v.z + v.w * v.w);
  float mu = sum * (1.f / 256);
  float rs = rsqrtf(ssq * (1.f / 256) - mu * mu + 1e-5f);
  const float4 gg = *(const float4*)(g + lane * 4);
  const float4 bb = *(const float4*)(b + lane * 4);
  ushort4 o;
  o.x = f2bb((v.x - mu) * rs * gg.x + bb.x);
  o.y = f2bb((v.y - mu) * rs * gg.y + bb.y);
  o.z = f2bb((v.z - mu) * rs * gg.z + bb.z);
  o.w = f2bb((v.w - mu) * rs * gg.w + bb.w);
  *(ushort4*)(mln + row * 256 + lane * 4) = o;
}

// ---------- kernel 3: MFMA GEMM  mln[32768x256] @ Wcat[256x1024] -> q/k/vt/g ----------
__global__ __launch_bounds__(256) void k_proj(const u16* __restrict__ mln,
                                              const u16* __restrict__ wcat_t,
                                              const float* __restrict__ bg,
                                              u16* __restrict__ qb,
                                              u16* __restrict__ kbuf,
                                              u16* __restrict__ vt,
                                              u16* __restrict__ gb) {
  __shared__ __align__(16) u16 A_l[64 * 256];
  __shared__ __align__(16) u16 B_l[64 * 256];
  int tid = threadIdx.x;
  int grow0 = blockIdx.x * 64;
  int hdt0 = blockIdx.y * 64;
#pragma unroll
  for (int it = 0; it < 8; it++) {
    int idx = it * 256 + tid;
    int row = idx >> 5, c8 = idx & 31;
    uint4 a = *(const uint4*)(mln + (size_t)(grow0 + row) * 256 + c8 * 8);
    *(uint4*)((char*)A_l + row * 512 + ((c8 ^ (row & 7)) << 4)) = a;
    uint4 bv = *(const uint4*)(wcat_t + (size_t)(hdt0 + row) * 256 + c8 * 8);
    *(uint4*)((char*)B_l + row * 512 + ((c8 ^ (row & 7)) << 4)) = bv;
  }
  __syncthreads();
  int w = tid >> 6, l = tid & 63;
  int l15 = l & 15, lg = l >> 4;
  f32x4 acc[4];
#pragma unroll
  for (int i = 0; i < 4; i++) acc[i] = (f32x4){0.f, 0.f, 0.f, 0.f};
#pragma unroll
  for (int ks = 0; ks < 8; ks++) {
    int rb = w * 16 + l15;
    short8 bf = *(const short8*)((char*)B_l + rb * 512 + (((ks * 4 + lg) ^ (rb & 7)) << 4));
#pragma unroll
    for (int mi = 0; mi < 4; mi++) {
      int ra = mi * 16 + l15;
      short8 af = *(const short8*)((char*)A_l + ra * 512 + (((ks * 4 + lg) ^ (ra & 7)) << 4));
      acc[mi] = __builtin_amdgcn_mfma_f32_16x16x32_bf16(af, bf, acc[mi], 0, 0, 0);
    }
  }
  int mat = blockIdx.y >> 2;
  int hdp = hdt0 + w * 16 + l15;
  int hd = hdp & 255;
  int h = hd >> 5, d = hd & 31;
  float bgv = (mat == 3) ? bg[hd] : 0.f;
#pragma unroll
  for (int mi = 0; mi < 4; mi++) {
#pragma unroll
    for (int j = 0; j < 4; j++) {
      int rowg = grow0 + mi * 16 + lg * 4 + j;
      int s = rowg >> 8, r = rowg & 255;
      float val = acc[mi][j];
      if (mat == 0)
        qb[((size_t)(s * 8 + h) * 256 + r) * 32 + d] = f2bb(val);
      else if (mat == 1)
        kbuf[((size_t)(s * 8 + h) * 256 + r) * 32 + d] = f2bb(val);
      else if (mat == 2)
        vt[((size_t)(s * 8 + h) * 32 + d) * 256 + r] = f2bb(val);
      else
        gb[(size_t)rowg * 256 + hd] = f2bb(1.0f / (1.0f + __expf(-(val + bgv))));
    }
  }
}

// ---------- kernel 4: MFMA flash attention per (s,h); writes og = (o/l)*g bf16 ----------
__global__ __launch_bounds__(256) void k_attn(const u16* __restrict__ qb,
                                              const u16* __restrict__ kbuf,
                                              const u16* __restrict__ vt,
                                              const u16* __restrict__ gb,
                                              const float* __restrict__ zb,
                                              const float* __restrict__ mask,
                                              u16* __restrict__ og) {
  __shared__ __align__(16) u16 P_l[4][64 * 72];  // per-wave, stride 72 (9x16B)
  int blk = blockIdx.x;
  int s = blk >> 3, h = blk & 7;
  int tid = threadIdx.x, w = tid >> 6, l = tid & 63;
  int l15 = l & 15, lg = l >> 4;
  int q0 = w * 64;
  size_t base = (size_t)(s * 8 + h) * 256 * 32;
  short8 qm[4];
#pragma unroll
  for (int mi = 0; mi < 4; mi++)
    qm[mi] = *(const short8*)(qb + base + (size_t)(q0 + mi * 16 + l15) * 32 + lg * 8);
  const float* zrow = zb + (size_t)h * 65536;
  const float* mrow = mask + s * 256;
  f32x4 oacc[4][2];
  float lsum[4][4];
#pragma unroll
  for (int mi = 0; mi < 4; mi++) {
#pragma unroll
    for (int n = 0; n < 2; n++) oacc[mi][n] = (f32x4){0.f, 0.f, 0.f, 0.f};
#pragma unroll
    for (int j = 0; j < 4; j++) lsum[mi][j] = 0.f;
  }
  u16* Pw = P_l[w];
#pragma unroll
  for (int kb4 = 0; kb4 < 4; kb4++) {
    // ---- QK^T ----
    f32x4 sc[4][4];
#pragma unroll
    for (int ni = 0; ni < 4; ni++) {
      short8 kf = *(const short8*)(kbuf + base + (size_t)(kb4 * 64 + ni * 16 + l15) * 32 + lg * 8);
#pragma unroll
      for (int mi = 0; mi < 4; mi++)
        sc[mi][ni] = __builtin_amdgcn_mfma_f32_16x16x32_bf16(
            qm[mi], kf, (f32x4){0.f, 0.f, 0.f, 0.f}, 0, 0, 0);
    }
    // ---- bias + exp + P write + partial row-sum ----
#pragma unroll
    for (int ni = 0; ni < 4; ni++) {
      int col = kb4 * 64 + ni * 16 + l15;
      float mb = 1e9f * (mrow[col] - 1.0f);
#pragma unroll
      for (int mi = 0; mi < 4; mi++) {
#pragma unroll
        for (int j = 0; j < 4; j++) {
          int rowq = q0 + mi * 16 + lg * 4 + j;
          float sv = sc[mi][ni][j] + zrow[(size_t)rowq * 256 + col] + mb;
          float p = __expf(sv);  // scores O(1): no max subtraction
          lsum[mi][j] += p;
          Pw[(mi * 16 + lg * 4 + j) * 72 + ni * 16 + l15] = f2bb(p);
        }
      }
    }
    // ---- P @ V (B-frags straight from global vt[d][k]) ----
#pragma unroll
    for (int ks = 0; ks < 2; ks++) {
#pragma unroll
      for (int n2 = 0; n2 < 2; n2++) {
        short8 vf = *(const short8*)(vt + (size_t)(s * 8 + h) * 32 * 256 +
                                     (size_t)(n2 * 16 + l15) * 256 + kb4 * 64 + ks * 32 + lg * 8);
#pragma unroll
        for (int mi = 0; mi < 4; mi++) {
          short8 pa = *(const short8*)((char*)Pw + (mi * 16 + l15) * 144 + ks * 64 + lg * 16);
          oacc[mi][n2] = __builtin_amdgcn_mfma_f32_16x16x32_bf16(pa, vf, oacc[mi][n2], 0, 0, 0);
        }
      }
    }
  }
  // ---- row-sum reduce across the 16 lanes sharing lg ----
#pragma unroll
  for (int mi = 0; mi < 4; mi++) {
#pragma unroll
    for (int j = 0; j < 4; j++) {
      float v = lsum[mi][j];
      v += __shfl_xor(v, 1, 64);
      v += __shfl_xor(v, 2, 64);
      v += __shfl_xor(v, 4, 64);
      v += __shfl_xor(v, 8, 64);
      lsum[mi][j] = v;
    }
  }
  // ---- normalize, gate, store og ----
#pragma unroll
  for (int mi = 0; mi < 4; mi++) {
#pragma unroll
    for (int j = 0; j < 4; j++) {
      float inv = 1.0f / lsum[mi][j];
      int rowq = q0 + mi * 16 + lg * 4 + j;
      size_t ob = ((size_t)s * 256 + rowq) * 256 + h * 32;
#pragma unroll
      for (int n2 = 0; n2 < 2; n2++) {
        int d = n2 * 16 + l15;
        float gv = b2f(gb[ob + d]);
        og[ob + d] = f2bb(oacc[mi][n2][j] * inv * gv);
      }
    }
  }
}

// ---------- kernel 5: MFMA GEMM  og[32768x256] @ WO[256x256] + bo -> out f32 ----------
__global__ __launch_bounds__(256) void k_out(const u16* __restrict__ og,
                                             const u16* __restrict__ wot,
                                             const float* __restrict__ bo,
                                             float* __restrict__ out) {
  __shared__ __align__(16) u16 A_l[64 * 256];
  __shared__ __align__(16) u16 B_l[64 * 256];
  int tid = threadIdx.x;
  int grow0 = blockIdx.x * 64, ct0 = blockIdx.y * 64;
#pragma unroll
  for (int it = 0; it < 8; it++) {
    int idx = it * 256 + tid;
    int row = idx >> 5, c8 = idx & 31;
    uint4 a = *(const uint4*)(og + (size_t)(grow0 + row) * 256 + c8 * 8);
    *(uint4*)((char*)A_l + row * 512 + ((c8 ^ (row & 7)) << 4)) = a;
    uint4 bv = *(const uint4*)(wot + (size_t)(ct0 + row) * 256 + c8 * 8);
    *(uint4*)((char*)B_l + row * 512 + ((c8 ^ (row & 7)) << 4)) = bv;
  }
  __syncthreads();
  int w = tid >> 6, l = tid & 63, l15 = l & 15, lg = l >> 4;
  f32x4 acc[4];
#pragma unroll
  for (int i = 0; i < 4; i++) acc[i] = (f32x4){0.f, 0.f, 0.f, 0.f};
#pragma unroll
  for (int ks = 0; ks < 8; ks++) {
    int rb = w * 16 + l15;
    short8 bf = *(const short8*)((char*)B_l + rb * 512 + (((ks * 4 + lg) ^ (rb & 7)) << 4));
#pragma unroll
    for (int mi = 0; mi < 4; mi++) {
      int ra = mi * 16 + l15;
      short8 af = *(const short8*)((char*)A_l + ra * 512 + (((ks * 4 + lg) ^ (ra & 7)) << 4));
      acc[mi] = __builtin_amdgcn_mfma_f32_16x16x32_bf16(af, bf, acc[mi], 0, 0, 0);
    }
  }
  int cout = ct0 + w * 16 + l15;
  float bov = bo[cout];
#pragma unroll
  for (int mi = 0; mi < 4; mi++) {
#pragma unroll
    for (int j = 0; j < 4; j++)
      out[(size_t)(grow0 + mi * 16 + lg * 4 + j) * 256 + cout] = acc[mi][j] + bov;
  }
}

extern "C" void kernel_launch(void* const* d_in, const int* in_sizes, int n_in,
                              void* d_out, int out_size, void* d_ws, size_t ws_size,
                              hipStream_t stream) {
  const float* m      = (const float*)d_in[0];
  const float* z      = (const float*)d_in[1];
  const float* mask   = (const float*)d_in[2];
  const float* ln_m_g = (const float*)d_in[3];
  const float* ln_m_b = (const float*)d_in[4];
  const float* ln_z_g = (const float*)d_in[5];
  const float* ln_z_b = (const float*)d_in[6];
  const float* wz     = (const float*)d_in[7];
  const float* wq     = (const float*)d_in[8];
  const float* wk     = (const float*)d_in[9];
  const float* wv     = (const float*)d_in[10];
  const float* wg     = (const float*)d_in[11];
  const float* bg     = (const float*)d_in[12];
  const float* wo     = (const float*)d_in[13];
  const float* bo     = (const float*)d_in[14];
  float* out = (float*)d_out;

  char* ws = (char*)d_ws;
  const size_t MiB = 1u << 20;
  float* zbuf  = (float*)(ws);                    // 2 MiB
  u16* wcat_t  = (u16*)(ws + 2 * MiB);            // 512 KiB  [1024 hd'][256 c]
  u16* wot     = (u16*)(ws + 2 * MiB + 512 * 1024); // 128 KiB [256 cout][256 hd]
  u16* mln     = (u16*)(ws + 3 * MiB);            // 16 MiB
  u16* qb      = (u16*)(ws + 19 * MiB);           // 16 MiB  [s][h][r][d]
  u16* kb      = (u16*)(ws + 35 * MiB);           // 16 MiB  [s][h][r][d]
  u16* vt      = (u16*)(ws + 51 * MiB);           // 16 MiB  [s][h][d][r]
  u16* gb      = (u16*)(ws + 67 * MiB);           // 16 MiB  [row][hd]
  u16* ogb     = (u16*)(ws + 83 * MiB);           // 16 MiB  [row][hd]
  (void)in_sizes; (void)n_in; (void)out_size; (void)ws_size;

  k_prep<<<dim3(16, 5), 256, 0, stream>>>(wq, wk, wv, wg, wo, wcat_t, wot);
  k_zbias<<<(R * R) / 4, 256, 0, stream>>>(z, ln_z_g, ln_z_b, wz, zbuf);
  k_lnm<<<(S * R) / 4, 256, 0, stream>>>(m, ln_m_g, ln_m_b, mln);
  k_proj<<<dim3(512, 16), 256, 0, stream>>>(mln, wcat_t, bg, qb, kb, vt, gb);
  k_attn<<<S * H, 256, 0, stream>>>(qb, kb, vt, gb, zbuf, mask, ogb);
  k_out<<<dim3(512, 4), 256, 0, stream>>>(ogb, wot, bo, out);
}

// Round 4
// 164.132 us; speedup vs baseline: 3.8482x; 1.2443x over previous
//
#include <hip/hip_runtime.h>
#include <stdint.h>

#define S 128
#define R 256
#define CM 256
#define CZ 128
#define H 8
#define D 32

typedef __attribute__((ext_vector_type(8))) short short8;
typedef __attribute__((ext_vector_type(4))) float f32x4;
typedef unsigned short u16;

// ---------- helpers ----------
__device__ __forceinline__ float wsum(float v) {
#pragma unroll
  for (int o = 32; o > 0; o >>= 1) v += __shfl_xor(v, o, 64);
  return v;
}
__device__ __forceinline__ u16 f2bb(float f) {
  unsigned u = __float_as_uint(f);
  return (u16)((u + 0x7fffu + ((u >> 16) & 1u)) >> 16);
}
__device__ __forceinline__ float b2f(u16 u) {
  return __uint_as_float(((unsigned)u) << 16);
}
__device__ __forceinline__ void gl_lds16(const u16* g, u16* l) {
  __builtin_amdgcn_global_load_lds(
      (const __attribute__((address_space(1))) unsigned int*)g,
      (__attribute__((address_space(3))) unsigned int*)l, 16, 0, 0);
}

// stage a [128 rows][64 cols] bf16 tile (src row stride 256 elems) into linear LDS.
// LDS slot (row, c8) receives global 16B-slot (c8 ^ (row&7))  [inverse-swizzled source]
__device__ __forceinline__ void stage_tile(const u16* __restrict__ src, u16* lbase,
                                           int w, int l) {
#pragma unroll
  for (int it = 0; it < 4; it++) {
    int rbase = it * 32 + w * 8;
    int row = rbase + (l >> 3);
    int gc8 = (l & 7) ^ (row & 7);
    gl_lds16(src + (size_t)row * 256 + gc8 * 8, lbase + rbase * 64);
  }
}

// ---------- kernel 0: weights -> bf16, transposed [hd'][c]; qscale folded ----------
__global__ __launch_bounds__(256) void k_prep(const float* __restrict__ wq,
                                              const float* __restrict__ wk,
                                              const float* __restrict__ wv,
                                              const float* __restrict__ wg,
                                              const float* __restrict__ wo,
                                              u16* __restrict__ wcat_t,
                                              u16* __restrict__ wot) {
  __shared__ float t[64][65];
  int mat = blockIdx.y;  // 0..4
  const float* src = (mat == 0) ? wq : (mat == 1) ? wk : (mat == 2) ? wv
                     : (mat == 3) ? wg : wo;
  float scale = (mat == 0) ? 0.17677669529663687f : 1.0f;  // 1/sqrt(D) into wq
  u16* dst = (mat < 4) ? (wcat_t + mat * 256 * 256) : wot;
  int ti = blockIdx.x >> 2, tj = blockIdx.x & 3;
  int tid = threadIdx.x;
  int cc = tid & 63, rr4 = tid >> 6;
#pragma unroll
  for (int it = 0; it < 16; it++) {
    int ic = it * 4 + rr4;
    t[ic][cc] = src[(tj * 64 + ic) * 256 + ti * 64 + cc];
  }
  __syncthreads();
#pragma unroll
  for (int it = 0; it < 16; it++) {
    int oh = it * 4 + rr4;
    dst[(ti * 64 + oh) * 256 + tj * 64 + cc] = f2bb(t[cc][oh] * scale);
  }
}

// ---------- kernel 1: pair bias ----------
__global__ __launch_bounds__(256) void k_zbias(const float* __restrict__ z,
                                               const float* __restrict__ lng,
                                               const float* __restrict__ lnb,
                                               const float* __restrict__ wz,
                                               float* __restrict__ zb) {
  int pair = blockIdx.x * 4 + (threadIdx.x >> 6);
  int lane = threadIdx.x & 63;
  const float* zrow = z + (size_t)pair * CZ;
  float x0 = zrow[lane], x1 = zrow[lane + 64];
  float sum = wsum(x0 + x1);
  float ssq = wsum(x0 * x0 + x1 * x1);
  float mu = sum * (1.0f / CZ);
  float rs = rsqrtf(ssq * (1.0f / CZ) - mu * mu + 1e-5f);
  float n0 = (x0 - mu) * rs * lng[lane] + lnb[lane];
  float n1 = (x1 - mu) * rs * lng[lane + 64] + lnb[lane + 64];
  float ph[8];
#pragma unroll
  for (int h = 0; h < 8; h++)
    ph[h] = n0 * wz[lane * 8 + h] + n1 * wz[(lane + 64) * 8 + h];
#pragma unroll
  for (int h = 0; h < 8; h++) ph[h] = wsum(ph[h]);
  if (lane == 0) {
#pragma unroll
    for (int h = 0; h < 8; h++) zb[h * (R * R) + pair] = ph[h];
  }
}

// ---------- kernel 2: LN(m) -> bf16 ----------
__global__ __launch_bounds__(256) void k_lnm(const float* __restrict__ m,
                                             const float* __restrict__ g,
                                             const float* __restrict__ b,
                                             u16* __restrict__ mln) {
  int w = threadIdx.x >> 6, lane = threadIdx.x & 63;
  size_t row = (size_t)blockIdx.x * 4 + w;
  const float4 v = *(const float4*)(m + row * 256 + lane * 4);
  float sum = wsum(v.x + v.y + v.z + v.w);
  float ssq = wsum(v.x * v.x + v.y * v.y + v.z * v.z + v.w * v.w);
  float mu = sum * (1.f / 256);
  float rs = rsqrtf(ssq * (1.f / 256) - mu * mu + 1e-5f);
  const float4 gg = *(const float4*)(g + lane * 4);
  const float4 bb = *(const float4*)(b + lane * 4);
  ushort4 o;
  o.x = f2bb((v.x - mu) * rs * gg.x + bb.x);
  o.y = f2bb((v.y - mu) * rs * gg.y + bb.y);
  o.z = f2bb((v.z - mu) * rs * gg.z + bb.z);
  o.w = f2bb((v.w - mu) * rs * gg.w + bb.w);
  *(ushort4*)(mln + row * 256 + lane * 4) = o;
}

// ---------- kernel 3: 128x128-tile MFMA GEMM  mln @ Wcat -> q/k/vt/g ----------
__global__ __launch_bounds__(256) void k_proj(const u16* __restrict__ mln,
                                              const u16* __restrict__ wcat_t,
                                              const float* __restrict__ bg,
                                              u16* __restrict__ qb,
                                              u16* __restrict__ kbuf,
                                              u16* __restrict__ vt,
                                              u16* __restrict__ gb) {
  __shared__ __align__(16) u16 lds[4 * 8192];  // A0 A1 B0 B1 (16KB each)
  int tid = threadIdx.x;
  int w = tid >> 6, l = tid & 63;
  int l15 = l & 15, lg = l >> 4;
  int wr = w >> 1, wc = w & 1;
  int grow0 = blockIdx.x * 128;
  int hdt0 = blockIdx.y * 128;
  const u16* asrc = mln + (size_t)grow0 * 256;
  const u16* bsrc = wcat_t + (size_t)hdt0 * 256;

  stage_tile(asrc, lds, w, l);
  stage_tile(bsrc, lds + 16384, w, l);
  __syncthreads();

  f32x4 acc[4][4];
#pragma unroll
  for (int mi = 0; mi < 4; mi++)
#pragma unroll
    for (int ni = 0; ni < 4; ni++) acc[mi][ni] = (f32x4){0.f, 0.f, 0.f, 0.f};

#pragma unroll
  for (int kt = 0; kt < 4; kt++) {
    if (kt < 3) {
      stage_tile(asrc + (kt + 1) * 64, lds + ((kt + 1) & 1) * 8192, w, l);
      stage_tile(bsrc + (kt + 1) * 64, lds + 16384 + ((kt + 1) & 1) * 8192, w, l);
    }
    const u16* Ab = lds + (kt & 1) * 8192;
    const u16* Bb = lds + 16384 + (kt & 1) * 8192;
#pragma unroll
    for (int ks = 0; ks < 2; ks++) {
      short8 af[4], bf[4];
#pragma unroll
      for (int i = 0; i < 4; i++) {
        int ra = wr * 64 + i * 16 + l15;
        af[i] = *(const short8*)(Ab + ra * 64 + (((ks * 4 + lg) ^ (ra & 7)) << 3));
        int rb = wc * 64 + i * 16 + l15;
        bf[i] = *(const short8*)(Bb + rb * 64 + (((ks * 4 + lg) ^ (rb & 7)) << 3));
      }
#pragma unroll
      for (int mi = 0; mi < 4; mi++)
#pragma unroll
        for (int ni = 0; ni < 4; ni++)
          acc[mi][ni] =
              __builtin_amdgcn_mfma_f32_16x16x32_bf16(af[mi], bf[ni], acc[mi][ni], 0, 0, 0);
    }
    __syncthreads();
  }

  // ---- epilogue: re-stage through LDS for coalesced uint4 stores ----
  int by = blockIdx.y;
  int mat = by >> 1;            // 0:q 1:k 2:v(transposed) 3:g
  int s = grow0 >> 8, r0 = grow0 & 255;
  int hbase = (by & 1) * 128;
  u16* stg = lds;               // [128][136] bf16 (34.8 KB, reuses main bufs)

  if (mat == 2) {
    // stage transposed: stg[hd_loc][r_loc]
#pragma unroll
    for (int mi = 0; mi < 4; mi++)
#pragma unroll
      for (int ni = 0; ni < 4; ni++)
#pragma unroll
        for (int j = 0; j < 4; j++) {
          int rl = wr * 64 + mi * 16 + lg * 4 + j;
          int hl = wc * 64 + ni * 16 + l15;
          stg[hl * 136 + rl] = f2bb(acc[mi][ni][j]);
        }
    __syncthreads();
#pragma unroll
    for (int it = 0; it < 8; it++) {
      int idx = it * 256 + tid;
      int dl = idx >> 4, c = idx & 15;
      int hd = hbase + dl;
      uint4 val = *(const uint4*)(stg + dl * 136 + c * 8);
      *(uint4*)(vt + ((size_t)(s * 8 + (hd >> 5)) * 32 + (hd & 31)) * 256 + r0 + c * 8) = val;
    }
  } else {
    float bgv[4];
    if (mat == 3) {
#pragma unroll
      for (int ni = 0; ni < 4; ni++) bgv[ni] = bg[hbase + wc * 64 + ni * 16 + l15];
    }
#pragma unroll
    for (int mi = 0; mi < 4; mi++)
#pragma unroll
      for (int ni = 0; ni < 4; ni++)
#pragma unroll
        for (int j = 0; j < 4; j++) {
          int rl = wr * 64 + mi * 16 + lg * 4 + j;
          int hl = wc * 64 + ni * 16 + l15;
          float v = acc[mi][ni][j];
          if (mat == 3) v = 1.0f / (1.0f + __expf(-(v + bgv[ni])));
          stg[rl * 136 + hl] = f2bb(v);
        }
    __syncthreads();
#pragma unroll
    for (int it = 0; it < 8; it++) {
      int idx = it * 256 + tid;
      int rl = idx >> 4, c = idx & 15;
      uint4 val = *(const uint4*)(stg + rl * 136 + c * 8);
      int hd = hbase + c * 8;
      if (mat == 3) {
        *(uint4*)(gb + (size_t)(grow0 + rl) * 256 + hd) = val;
      } else {
        u16* dst = (mat == 0) ? qb : kbuf;
        *(uint4*)(dst + ((size_t)(s * 8 + (hd >> 5)) * 256 + r0 + rl) * 32 + (hd & 31)) = val;
      }
    }
  }
}

// ---------- kernel 4: MFMA flash attention per (s,h); writes og = (o/l)*g bf16 ----------
__global__ __launch_bounds__(256) void k_attn(const u16* __restrict__ qb,
                                              const u16* __restrict__ kbuf,
                                              const u16* __restrict__ vt,
                                              const u16* __restrict__ gb,
                                              const float* __restrict__ zb,
                                              const float* __restrict__ mask,
                                              u16* __restrict__ og) {
  __shared__ __align__(16) u16 P_l[4][64 * 72];  // per-wave, stride 72 (9x16B)
  int blk = blockIdx.x;
  int s = blk >> 3, h = blk & 7;
  int tid = threadIdx.x, w = tid >> 6, l = tid & 63;
  int l15 = l & 15, lg = l >> 4;
  int q0 = w * 64;
  size_t base = (size_t)(s * 8 + h) * 256 * 32;
  short8 qm[4];
#pragma unroll
  for (int mi = 0; mi < 4; mi++)
    qm[mi] = *(const short8*)(qb + base + (size_t)(q0 + mi * 16 + l15) * 32 + lg * 8);
  const float* zrow = zb + (size_t)h * 65536;
  const float* mrow = mask + s * 256;
  f32x4 oacc[4][2];
  float lsum[4][4];
#pragma unroll
  for (int mi = 0; mi < 4; mi++) {
#pragma unroll
    for (int n = 0; n < 2; n++) oacc[mi][n] = (f32x4){0.f, 0.f, 0.f, 0.f};
#pragma unroll
    for (int j = 0; j < 4; j++) lsum[mi][j] = 0.f;
  }
  u16* Pw = P_l[w];
#pragma unroll
  for (int kb4 = 0; kb4 < 4; kb4++) {
    f32x4 sc[4][4];
#pragma unroll
    for (int ni = 0; ni < 4; ni++) {
      short8 kf = *(const short8*)(kbuf + base + (size_t)(kb4 * 64 + ni * 16 + l15) * 32 + lg * 8);
#pragma unroll
      for (int mi = 0; mi < 4; mi++)
        sc[mi][ni] = __builtin_amdgcn_mfma_f32_16x16x32_bf16(
            qm[mi], kf, (f32x4){0.f, 0.f, 0.f, 0.f}, 0, 0, 0);
    }
#pragma unroll
    for (int ni = 0; ni < 4; ni++) {
      int col = kb4 * 64 + ni * 16 + l15;
      float mb = 1e9f * (mrow[col] - 1.0f);
#pragma unroll
      for (int mi = 0; mi < 4; mi++) {
#pragma unroll
        for (int j = 0; j < 4; j++) {
          int rowq = q0 + mi * 16 + lg * 4 + j;
          float sv = sc[mi][ni][j] + zrow[(size_t)rowq * 256 + col] + mb;
          float p = __expf(sv);  // scores O(1): no max subtraction
          lsum[mi][j] += p;
          Pw[(mi * 16 + lg * 4 + j) * 72 + ni * 16 + l15] = f2bb(p);
        }
      }
    }
#pragma unroll
    for (int ks = 0; ks < 2; ks++) {
#pragma unroll
      for (int n2 = 0; n2 < 2; n2++) {
        short8 vf = *(const short8*)(vt + (size_t)(s * 8 + h) * 32 * 256 +
                                     (size_t)(n2 * 16 + l15) * 256 + kb4 * 64 + ks * 32 + lg * 8);
#pragma unroll
        for (int mi = 0; mi < 4; mi++) {
          short8 pa = *(const short8*)((char*)Pw + (mi * 16 + l15) * 144 + ks * 64 + lg * 16);
          oacc[mi][n2] = __builtin_amdgcn_mfma_f32_16x16x32_bf16(pa, vf, oacc[mi][n2], 0, 0, 0);
        }
      }
    }
  }
#pragma unroll
  for (int mi = 0; mi < 4; mi++) {
#pragma unroll
    for (int j = 0; j < 4; j++) {
      float v = lsum[mi][j];
      v += __shfl_xor(v, 1, 64);
      v += __shfl_xor(v, 2, 64);
      v += __shfl_xor(v, 4, 64);
      v += __shfl_xor(v, 8, 64);
      lsum[mi][j] = v;
    }
  }
#pragma unroll
  for (int mi = 0; mi < 4; mi++) {
#pragma unroll
    for (int j = 0; j < 4; j++) {
      float inv = 1.0f / lsum[mi][j];
      int rowq = q0 + mi * 16 + lg * 4 + j;
      size_t ob = ((size_t)s * 256 + rowq) * 256 + h * 32;
#pragma unroll
      for (int n2 = 0; n2 < 2; n2++) {
        int d = n2 * 16 + l15;
        float gv = b2f(gb[ob + d]);
        og[ob + d] = f2bb(oacc[mi][n2][j] * inv * gv);
      }
    }
  }
}

// ---------- kernel 5: 128x128-tile MFMA GEMM  og @ WO + bo -> out f32 ----------
__global__ __launch_bounds__(256) void k_out(const u16* __restrict__ og,
                                             const u16* __restrict__ wot,
                                             const float* __restrict__ bo,
                                             float* __restrict__ out) {
  __shared__ __align__(16) u16 lds[4 * 8192];
  int tid = threadIdx.x;
  int w = tid >> 6, l = tid & 63;
  int l15 = l & 15, lg = l >> 4;
  int wr = w >> 1, wc = w & 1;
  int grow0 = blockIdx.x * 128;
  int ct0 = blockIdx.y * 128;
  const u16* asrc = og + (size_t)grow0 * 256;
  const u16* bsrc = wot + (size_t)ct0 * 256;

  stage_tile(asrc, lds, w, l);
  stage_tile(bsrc, lds + 16384, w, l);
  __syncthreads();

  f32x4 acc[4][4];
#pragma unroll
  for (int mi = 0; mi < 4; mi++)
#pragma unroll
    for (int ni = 0; ni < 4; ni++) acc[mi][ni] = (f32x4){0.f, 0.f, 0.f, 0.f};

#pragma unroll
  for (int kt = 0; kt < 4; kt++) {
    if (kt < 3) {
      stage_tile(asrc + (kt + 1) * 64, lds + ((kt + 1) & 1) * 8192, w, l);
      stage_tile(bsrc + (kt + 1) * 64, lds + 16384 + ((kt + 1) & 1) * 8192, w, l);
    }
    const u16* Ab = lds + (kt & 1) * 8192;
    const u16* Bb = lds + 16384 + (kt & 1) * 8192;
#pragma unroll
    for (int ks = 0; ks < 2; ks++) {
      short8 af[4], bf[4];
#pragma unroll
      for (int i = 0; i < 4; i++) {
        int ra = wr * 64 + i * 16 + l15;
        af[i] = *(const short8*)(Ab + ra * 64 + (((ks * 4 + lg) ^ (ra & 7)) << 3));
        int rb = wc * 64 + i * 16 + l15;
        bf[i] = *(const short8*)(Bb + rb * 64 + (((ks * 4 + lg) ^ (rb & 7)) << 3));
      }
#pragma unroll
      for (int mi = 0; mi < 4; mi++)
#pragma unroll
        for (int ni = 0; ni < 4; ni++)
          acc[mi][ni] =
              __builtin_amdgcn_mfma_f32_16x16x32_bf16(af[mi], bf[ni], acc[mi][ni], 0, 0, 0);
    }
    __syncthreads();
  }

  int cout_base = ct0 + wc * 64;
#pragma unroll
  for (int ni = 0; ni < 4; ni++) {
    int cout = cout_base + ni * 16 + l15;
    float bov = bo[cout];
#pragma unroll
    for (int mi = 0; mi < 4; mi++)
#pragma unroll
      for (int j = 0; j < 4; j++)
        out[(size_t)(grow0 + wr * 64 + mi * 16 + lg * 4 + j) * 256 + cout] =
            acc[mi][ni][j] + bov;
  }
}

extern "C" void kernel_launch(void* const* d_in, const int* in_sizes, int n_in,
                              void* d_out, int out_size, void* d_ws, size_t ws_size,
                              hipStream_t stream) {
  const float* m      = (const float*)d_in[0];
  const float* z      = (const float*)d_in[1];
  const float* mask   = (const float*)d_in[2];
  const float* ln_m_g = (const float*)d_in[3];
  const float* ln_m_b = (const float*)d_in[4];
  const float* ln_z_g = (const float*)d_in[5];
  const float* ln_z_b = (const float*)d_in[6];
  const float* wz     = (const float*)d_in[7];
  const float* wq     = (const float*)d_in[8];
  const float* wk     = (const float*)d_in[9];
  const float* wv     = (const float*)d_in[10];
  const float* wg     = (const float*)d_in[11];
  const float* bg     = (const float*)d_in[12];
  const float* wo     = (const float*)d_in[13];
  const float* bo     = (const float*)d_in[14];
  float* out = (float*)d_out;

  char* ws = (char*)d_ws;
  const size_t MiB = 1u << 20;
  float* zbuf  = (float*)(ws);                      // 2 MiB
  u16* wcat_t  = (u16*)(ws + 2 * MiB);              // 512 KiB  [1024 hd'][256 c]
  u16* wot     = (u16*)(ws + 2 * MiB + 512 * 1024); // 128 KiB  [256 cout][256 hd]
  u16* mln     = (u16*)(ws + 3 * MiB);              // 16 MiB
  u16* qb      = (u16*)(ws + 19 * MiB);             // 16 MiB  [s][h][r][d]
  u16* kb      = (u16*)(ws + 35 * MiB);             // 16 MiB  [s][h][r][d]
  u16* vt      = (u16*)(ws + 51 * MiB);             // 16 MiB  [s][h][d][r]
  u16* gb      = (u16*)(ws + 67 * MiB);             // 16 MiB  [row][hd]
  u16* ogb     = (u16*)(ws + 83 * MiB);             // 16 MiB  [row][hd]
  (void)in_sizes; (void)n_in; (void)out_size; (void)ws_size;

  k_prep<<<dim3(16, 5), 256, 0, stream>>>(wq, wk, wv, wg, wo, wcat_t, wot);
  k_zbias<<<(R * R) / 4, 256, 0, stream>>>(z, ln_z_g, ln_z_b, wz, zbuf);
  k_lnm<<<(S * R) / 4, 256, 0, stream>>>(m, ln_m_g, ln_m_b, mln);
  k_proj<<<dim3(256, 8), 256, 0, stream>>>(mln, wcat_t, bg, qb, kb, vt, gb);
  k_attn<<<S * H, 256, 0, stream>>>(qb, kb, vt, gb, zbuf, mask, ogb);
  k_out<<<dim3(256, 2), 256, 0, stream>>>(ogb, wot, bo, out);
}